// Round 1
// baseline (72.861 us; speedup 1.0000x reference)
//
#include <hip/hip_runtime.h>

// KalmanGain: B=262144 batches, N=8 state, M=4 measurement. All fp32.
// One thread per batch; all small-matrix algebra in registers.
// Sigma = F Sp F^T + Q ; A = Sigma H^T ; S = H A + R ; KG = A inv(S).
// Register economy: never materialize Sigma. A = F*(Sp*(H F)^T) + Q*H^T,
// with Sp and Q streamed row-by-row.

__global__ __launch_bounds__(256) void kalman_gain_kernel(
    const float* __restrict__ Fg, const float* __restrict__ Hg,
    const float* __restrict__ Spg, const float* __restrict__ Qg,
    const float* __restrict__ Rg, float* __restrict__ out, int nb)
{
    int b = blockIdx.x * blockDim.x + threadIdx.x;
    if (b >= nb) return;

    const float4* F4  = reinterpret_cast<const float4*>(Fg  + (size_t)b * 64);
    const float4* H4  = reinterpret_cast<const float4*>(Hg  + (size_t)b * 32);
    const float4* Sp4 = reinterpret_cast<const float4*>(Spg + (size_t)b * 64);
    const float4* Q4  = reinterpret_cast<const float4*>(Qg  + (size_t)b * 64);
    const float4* R4  = reinterpret_cast<const float4*>(Rg  + (size_t)b * 16);

    // ---- load H [4][8] ----
    float h[32];
    #pragma unroll
    for (int i = 0; i < 8; ++i) {
        float4 v = H4[i];
        h[4*i+0] = v.x; h[4*i+1] = v.y; h[4*i+2] = v.z; h[4*i+3] = v.w;
    }

    // ---- load F [8][8] ----
    float f[64];
    #pragma unroll
    for (int i = 0; i < 16; ++i) {
        float4 v = F4[i];
        f[4*i+0] = v.x; f[4*i+1] = v.y; f[4*i+2] = v.z; f[4*i+3] = v.w;
    }

    // ---- HF = H @ F  [4][8] ----
    float hf[32];
    #pragma unroll
    for (int a = 0; a < 4; ++a) {
        #pragma unroll
        for (int k = 0; k < 8; ++k) {
            float acc = 0.f;
            #pragma unroll
            for (int bb = 0; bb < 8; ++bb)
                acc += h[a*8+bb] * f[bb*8+k];
            hf[a*8+k] = acc;
        }
    }

    // ---- W = Sp @ HF^T  [8][4], stream Sp rows ----
    float w[32];
    #pragma unroll
    for (int i = 0; i < 8; ++i) {
        float4 r0 = Sp4[2*i], r1 = Sp4[2*i+1];
        float sp[8] = {r0.x, r0.y, r0.z, r0.w, r1.x, r1.y, r1.z, r1.w};
        #pragma unroll
        for (int j = 0; j < 4; ++j) {
            float acc = 0.f;
            #pragma unroll
            for (int k = 0; k < 8; ++k)
                acc += sp[k] * hf[j*8+k];
            w[i*4+j] = acc;
        }
    }

    // ---- A = F @ W  [8][4] ----
    float A[32];
    #pragma unroll
    for (int i = 0; i < 8; ++i) {
        #pragma unroll
        for (int j = 0; j < 4; ++j) {
            float acc = 0.f;
            #pragma unroll
            for (int k = 0; k < 8; ++k)
                acc += f[i*8+k] * w[k*4+j];
            A[i*4+j] = acc;
        }
    }

    // ---- A += Q @ H^T, stream Q rows ----
    #pragma unroll
    for (int i = 0; i < 8; ++i) {
        float4 r0 = Q4[2*i], r1 = Q4[2*i+1];
        float q[8] = {r0.x, r0.y, r0.z, r0.w, r1.x, r1.y, r1.z, r1.w};
        #pragma unroll
        for (int j = 0; j < 4; ++j) {
            float acc = 0.f;
            #pragma unroll
            for (int k = 0; k < 8; ++k)
                acc += q[k] * h[j*8+k];
            A[i*4+j] += acc;
        }
    }

    // ---- S = H @ A + R  [4][4] ----
    float s[16];
    #pragma unroll
    for (int i = 0; i < 4; ++i) {
        float4 v = R4[i];
        s[4*i+0] = v.x; s[4*i+1] = v.y; s[4*i+2] = v.z; s[4*i+3] = v.w;
    }
    #pragma unroll
    for (int p = 0; p < 4; ++p) {
        #pragma unroll
        for (int q = 0; q < 4; ++q) {
            float acc = 0.f;
            #pragma unroll
            for (int i = 0; i < 8; ++i)
                acc += h[p*8+i] * A[i*4+q];
            s[p*4+q] += acc;
        }
    }

    // ---- invert S (4x4 SPD) via unrolled Gauss-Jordan, no pivoting ----
    float is[16] = {1.f,0.f,0.f,0.f, 0.f,1.f,0.f,0.f, 0.f,0.f,1.f,0.f, 0.f,0.f,0.f,1.f};
    #pragma unroll
    for (int c = 0; c < 4; ++c) {
        float pinv = 1.0f / s[c*4+c];
        #pragma unroll
        for (int k = 0; k < 4; ++k) { s[c*4+k] *= pinv; is[c*4+k] *= pinv; }
        #pragma unroll
        for (int r = 0; r < 4; ++r) {
            if (r != c) {
                float fac = s[r*4+c];
                #pragma unroll
                for (int k = 0; k < 4; ++k) {
                    s[r*4+k]  -= fac * s[c*4+k];
                    is[r*4+k] -= fac * is[c*4+k];
                }
            }
        }
    }

    // ---- KG = A @ inv(S)  [8][4], store ----
    float4* out4 = reinterpret_cast<float4*>(out + (size_t)b * 32);
    #pragma unroll
    for (int i = 0; i < 8; ++i) {
        float4 o;
        o.x = A[i*4+0]*is[0] + A[i*4+1]*is[4] + A[i*4+2]*is[8]  + A[i*4+3]*is[12];
        o.y = A[i*4+0]*is[1] + A[i*4+1]*is[5] + A[i*4+2]*is[9]  + A[i*4+3]*is[13];
        o.z = A[i*4+0]*is[2] + A[i*4+1]*is[6] + A[i*4+2]*is[10] + A[i*4+3]*is[14];
        o.w = A[i*4+0]*is[3] + A[i*4+1]*is[7] + A[i*4+2]*is[11] + A[i*4+3]*is[15];
        out4[i] = o;
    }
}

extern "C" void kernel_launch(void* const* d_in, const int* in_sizes, int n_in,
                              void* d_out, int out_size, void* d_ws, size_t ws_size,
                              hipStream_t stream) {
    const float* F  = (const float*)d_in[0];
    const float* H  = (const float*)d_in[1];
    const float* Sp = (const float*)d_in[2];
    const float* Q  = (const float*)d_in[3];
    const float* R  = (const float*)d_in[4];
    float* out = (float*)d_out;

    int nb = in_sizes[0] / 64;  // B = 262144
    int threads = 256;
    int blocks = (nb + threads - 1) / threads;
    kalman_gain_kernel<<<blocks, threads, 0, stream>>>(F, H, Sp, Q, R, out, nb);
}